// Round 1
// baseline (187.854 us; speedup 1.0000x reference)
//
#include <hip/hip_runtime.h>
#include <hip/hip_bf16.h>
#include <cstdint>
#include <cfloat>

#define NTOK 16384
#define DIN  1024
#define DOUT 1024
#define NEXP 8
#define RLORA 16
#define KTOT 1152          // DIN + NEXP*RLORA
#define SCALE_LORA 2.0f    // alpha/rank = 32/16

typedef __attribute__((ext_vector_type(8))) short bf16x8;
typedef __attribute__((ext_vector_type(4))) float f32x4;

__device__ __forceinline__ unsigned short f2bf(float f) {
  __hip_bfloat16 h = __float2bfloat16(f);
  unsigned short u;
  __builtin_memcpy(&u, &h, 2);
  return u;
}

__device__ __forceinline__ void gld_lds16(const void* g, void* l) {
  __builtin_amdgcn_global_load_lds((const __attribute__((address_space(1))) void*)g,
                                   (__attribute__((address_space(3))) void*)l,
                                   16, 0, 0);
}

// ---------------------------------------------------------------------------
// Transpose Wcat = [W_base; Bcat]^T -> WcatT [1024][1152] bf16, LDS-tiled.
// ---------------------------------------------------------------------------
__global__ __launch_bounds__(256) void k_transW(const float* __restrict__ Wb,
                                                const float* __restrict__ B,
                                                unsigned short* __restrict__ WcatT) {
  __shared__ unsigned short T[64][66];
  const int k0 = blockIdx.x * 64, j0 = blockIdx.y * 64;
  const int t = threadIdx.x;
#pragma unroll
  for (int p = 0; p < 4; ++p) {
    int kk = p * 16 + (t >> 4);
    int c4 = (t & 15) * 4;
    int k = k0 + kk;
    const float* src = (k < 1024) ? (Wb + (size_t)k * 1024) : (B + (size_t)(k - 1024) * 1024);
    float4 v = *(const float4*)(src + j0 + c4);
    T[kk][c4 + 0] = f2bf(v.x); T[kk][c4 + 1] = f2bf(v.y);
    T[kk][c4 + 2] = f2bf(v.z); T[kk][c4 + 3] = f2bf(v.w);
  }
  __syncthreads();
#pragma unroll
  for (int p = 0; p < 2; ++p) {
    int jj = p * 32 + (t >> 3);
    int kc = (t & 7) * 8;
    unsigned short buf[8];
#pragma unroll
    for (int i = 0; i < 8; ++i) buf[i] = T[kc + i][jj];
    uint4 u; __builtin_memcpy(&u, buf, 16);
    *(uint4*)(WcatT + (size_t)(j0 + jj) * KTOT + k0 + kc) = u;
  }
}

// ---------------------------------------------------------------------------
// AcatT[e*16+r][d] = A[e][d][r] bf16, LDS-tiled. grid (4, 8): (d-chunk, e).
// ---------------------------------------------------------------------------
__global__ __launch_bounds__(256) void k_transA(const float* __restrict__ A,
                                                unsigned short* __restrict__ AcatT) {
  __shared__ unsigned short T[256][17];
  const int e = blockIdx.y, d0 = blockIdx.x * 256;
  const int t = threadIdx.x;
#pragma unroll
  for (int p = 0; p < 4; ++p) {
    int idx = p * 256 + t;
    int d = idx >> 2;
    int rr = (idx & 3) * 4;
    float4 v = *(const float4*)(A + (size_t)e * 16384 + (size_t)(d0 + d) * 16 + rr);
    T[d][rr + 0] = f2bf(v.x); T[d][rr + 1] = f2bf(v.y);
    T[d][rr + 2] = f2bf(v.z); T[d][rr + 3] = f2bf(v.w);
  }
  __syncthreads();
#pragma unroll
  for (int p = 0; p < 2; ++p) {
    int slot = p * 256 + t;
    int r = slot >> 5;
    int dc = (slot & 31) * 8;
    unsigned short buf[8];
#pragma unroll
    for (int i = 0; i < 8; ++i) buf[i] = T[dc + i][r];
    uint4 u; __builtin_memcpy(&u, buf, 16);
    *(uint4*)(AcatT + (size_t)(e * 16 + r) * 1024 + d0 + dc) = u;
  }
}

// ---------------------------------------------------------------------------
// WgT[e][d] = Wg[d][e] fp32 (32 KB). grid(4), block(256).
// ---------------------------------------------------------------------------
__global__ __launch_bounds__(256) void k_transG(const float* __restrict__ Wg,
                                                float* __restrict__ WgT) {
  int d = blockIdx.x * 256 + threadIdx.x;
  float4 a = *(const float4*)(Wg + (size_t)d * 8);
  float4 b = *(const float4*)(Wg + (size_t)d * 8 + 4);
  WgT[0 * 1024 + d] = a.x; WgT[1 * 1024 + d] = a.y;
  WgT[2 * 1024 + d] = a.z; WgT[3 * 1024 + d] = a.w;
  WgT[4 * 1024 + d] = b.x; WgT[5 * 1024 + d] = b.y;
  WgT[6 * 1024 + d] = b.z; WgT[7 * 1024 + d] = b.w;
}

// ---------------------------------------------------------------------------
// Router: one wave per TWO tokens (ILP: WgT loads shared, two independent
// reduction chains). grid 2048.
// ---------------------------------------------------------------------------
__global__ __launch_bounds__(256) void k_router(const float* __restrict__ tokens,
                                                const float* __restrict__ WgT,
                                                float* __restrict__ out_logits,
                                                float* __restrict__ out_sel,
                                                float* __restrict__ out_w,
                                                unsigned short* __restrict__ Xcat,
                                                float4* __restrict__ gateinfo) {
  const int wid = threadIdx.x >> 6;
  const int lane = threadIdx.x & 63;
  const int t0 = (blockIdx.x * 4 + wid) * 2;

  float4 xa[4], xb[4];
  const float* x0 = tokens + (size_t)t0 * DIN;
  const float* x1 = x0 + DIN;
#pragma unroll
  for (int j = 0; j < 4; ++j) {
    xa[j] = *(const float4*)(x0 + j * 256 + lane * 4);
    xb[j] = *(const float4*)(x1 + j * 256 + lane * 4);
  }

#pragma unroll
  for (int tt = 0; tt < 2; ++tt) {
    unsigned short* xbp = Xcat + (size_t)(t0 + tt) * KTOT;
    const float4* xv = tt ? xb : xa;
#pragma unroll
    for (int j = 0; j < 4; ++j) {
      const float* xf = (const float*)&xv[j];
      unsigned short hb[4];
#pragma unroll
      for (int m = 0; m < 4; ++m) hb[m] = f2bf(xf[m]);
      uint2 u;
      __builtin_memcpy(&u, hb, 8);
      *(uint2*)(xbp + j * 256 + lane * 4) = u;
    }
  }

  float accA[8] = {0,0,0,0,0,0,0,0}, accB[8] = {0,0,0,0,0,0,0,0};
#pragma unroll
  for (int j = 0; j < 4; ++j) {
#pragma unroll
    for (int e = 0; e < 8; ++e) {
      float4 wv = *(const float4*)(WgT + (size_t)e * 1024 + j * 256 + lane * 4);
      accA[e] = fmaf(xa[j].x, wv.x, fmaf(xa[j].y, wv.y,
                fmaf(xa[j].z, wv.z, fmaf(xa[j].w, wv.w, accA[e]))));
      accB[e] = fmaf(xb[j].x, wv.x, fmaf(xb[j].y, wv.y,
                fmaf(xb[j].z, wv.z, fmaf(xb[j].w, wv.w, accB[e]))));
    }
  }
#pragma unroll
  for (int s = 1; s < 64; s <<= 1) {
#pragma unroll
    for (int e = 0; e < 8; ++e) {
      accA[e] += __shfl_xor(accA[e], s, 64);
      accB[e] += __shfl_xor(accB[e], s, 64);
    }
  }

#pragma unroll
  for (int tt = 0; tt < 2; ++tt) {
    const float* acc = tt ? accB : accA;
    int t = t0 + tt;
    float v0 = -FLT_MAX, v1 = -FLT_MAX;
    int i0 = -1, i1 = -1;
#pragma unroll
    for (int e = 0; e < 8; ++e) {
      float v = acc[e];
      if (v > v0) { v1 = v0; i1 = i0; v0 = v; i0 = e; }
      else if (v > v1) { v1 = v; i1 = e; }
    }
    float ex = expf(v1 - v0);
    float inv = 1.0f / (1.0f + ex);
    float w0 = inv, w1 = ex * inv;
    if (lane == 0) {
      float4* lg = (float4*)(out_logits + (size_t)t * 8);
      lg[0] = make_float4(acc[0], acc[1], acc[2], acc[3]);
      lg[1] = make_float4(acc[4], acc[5], acc[6], acc[7]);
      *(float2*)(out_sel + (size_t)t * 2) = make_float2((float)i0, (float)i1);
      *(float2*)(out_w + (size_t)t * 2) = make_float2(w0, w1);
      gateinfo[t] = make_float4((float)i0, (float)i1, w0 * SCALE_LORA, w1 * SCALE_LORA);
    }
  }
}

// ---------------------------------------------------------------------------
// H-GEMM + gating. BM=64, BN=64, BK=64 (h-loop keeps regs flat), grid 512.
// 8 MFMA per wave per barrier-pair (2x R3).
// ---------------------------------------------------------------------------
__global__ __launch_bounds__(256) void k_hgemm(const unsigned short* __restrict__ Xg,
                                               const unsigned short* __restrict__ Ag,
                                               const float4* __restrict__ gateinfo,
                                               unsigned short* __restrict__ Xout) {
  constexpr int BK = 64;
  __shared__ alignas(16) unsigned short As[64 * BK];
  __shared__ alignas(16) unsigned short Bs[64 * BK];
  const int tid = threadIdx.x;
  const int lane = tid & 63;
  const int wid = tid >> 6;
  const int id = blockIdx.x;
  const int xcd = id & 7, s5 = id >> 3;
  const int n0 = (s5 & 1) * 64;
  const int m0 = (xcd * 32 + (s5 >> 1)) * 64;
  const int wm = (wid >> 1) * 32, wn = (wid & 1) * 32;
  const int quad = lane >> 4, r16 = lane & 15;

  f32x4 acc[2][2] = {};

  for (int k0 = 0; k0 < 1024; k0 += BK) {
#pragma unroll
    for (int i = 0; i < 2; ++i) {          // A: 64 rows x 8 chunks = 512
      int s = i * 256 + tid;
      int r = s >> 3, c = s & 7;
      int q = c ^ ((r >> 1) & 7);
      gld_lds16(Xg + (size_t)(m0 + r) * KTOT + k0 + q * 8, (char*)As + s * 16);
    }
#pragma unroll
    for (int i = 0; i < 2; ++i) {          // B: 64 rows x 8 chunks
      int s = i * 256 + tid;
      int r = s >> 3, c = s & 7;
      int q = c ^ ((r >> 1) & 7);
      gld_lds16(Ag + (size_t)(n0 + r) * 1024 + k0 + q * 8, (char*)Bs + s * 16);
    }
    __syncthreads();

#pragma unroll
    for (int h = 0; h < 2; ++h) {
      bf16x8 af[2], bfr[2];
#pragma unroll
      for (int mi = 0; mi < 2; ++mi) {
        int m = wm + mi * 16 + r16;
        int slot = m * 8 + ((h * 4 + quad) ^ ((m >> 1) & 7));
        af[mi] = *(const bf16x8*)((const char*)As + slot * 16);
      }
#pragma unroll
      for (int ni = 0; ni < 2; ++ni) {
        int n = wn + ni * 16 + r16;
        int slot = n * 8 + ((h * 4 + quad) ^ ((n >> 1) & 7));
        bfr[ni] = *(const bf16x8*)((const char*)Bs + slot * 16);
      }
#pragma unroll
      for (int mi = 0; mi < 2; ++mi)
#pragma unroll
        for (int ni = 0; ni < 2; ++ni)
          acc[mi][ni] = __builtin_amdgcn_mfma_f32_16x16x32_bf16(af[mi], bfr[ni], acc[mi][ni], 0, 0, 0);
    }
    __syncthreads();
  }

#pragma unroll
  for (int mi = 0; mi < 2; ++mi)
#pragma unroll
    for (int r = 0; r < 4; ++r) {
      int row = m0 + wm + mi * 16 + quad * 4 + r;
      float4 gi = gateinfo[row];
      int ie0 = (int)gi.x, ie1 = (int)gi.y;
#pragma unroll
      for (int ni = 0; ni < 2; ++ni) {
        int c = n0 + wn + ni * 16 + r16;
        int e = c >> 4;
        float h = acc[mi][ni][r];
        float v = (e == ie0) ? gi.z * h : ((e == ie1) ? gi.w * h : 0.f);
        Xout[(size_t)row * KTOT + 1024 + c] = f2bf(v);
      }
    }
}

// ---------------------------------------------------------------------------
// Main GEMM: out = Xcat @ WcatT^T. 256x256 tile, BK=64, 8 waves (2Mx4N),
// double-buffered LDS (128 KB), counted vmcnt(8) pipeline (T3/T4), raw
// s_barrier (no vmcnt(0) drain), setprio around MFMA cluster (T5).
// 64 MFMA per wave per barrier-pair; 18 K-steps. Grid 256 = 1 block/CU.
// ---------------------------------------------------------------------------
__global__ __launch_bounds__(512, 2) void k_gemm_main(const unsigned short* __restrict__ Xg,
                                                      const unsigned short* __restrict__ Wg,
                                                      float* __restrict__ C) {
  __shared__ alignas(16) unsigned short As[2][256 * 64];  // 64 KB
  __shared__ alignas(16) unsigned short Bs[2][256 * 64];  // 64 KB
  const int tid = threadIdx.x;
  const int lane = tid & 63;
  const int wid = tid >> 6;
  const int id = blockIdx.x;
  const int xcd = id & 7, loc = id >> 3;
  const int gid = xcd * 32 + loc;           // bijective: 256 % 8 == 0
  const int m0 = (gid >> 2) * 256;          // 64 m-tiles
  const int n0 = (gid & 3) * 256;           // 4 n-tiles
  const int wm = (wid >> 2) * 128, wn = (wid & 3) * 64;
  const int quad = lane >> 4, r16 = lane & 15;

  f32x4 acc[8][4] = {};
  constexpr int NK = KTOT / 64;             // 18

  // Stage K-tile kt into dbuf d: 8 gld_lds per thread (4 A + 4 B).
  // Source pre-swizzled (q = c ^ ((r>>1)&7)) so linear LDS dest holds the
  // swizzled layout the frag reads expect (both-sides-or-neither, rule #21).
#define STAGE(d, kt)                                                          \
  {                                                                           \
    const int k0s = (kt) * 64;                                                \
    _Pragma("unroll")                                                         \
    for (int i = 0; i < 4; ++i) {                                             \
      int s = i * 512 + tid;                                                  \
      int r = s >> 3, c = s & 7;                                              \
      int q = c ^ ((r >> 1) & 7);                                             \
      gld_lds16(Xg + (size_t)(m0 + r) * KTOT + k0s + q * 8,                   \
                (char*)As[d] + s * 16);                                       \
    }                                                                         \
    _Pragma("unroll")                                                         \
    for (int i = 0; i < 4; ++i) {                                             \
      int s = i * 512 + tid;                                                  \
      int r = s >> 3, c = s & 7;                                              \
      int q = c ^ ((r >> 1) & 7);                                             \
      gld_lds16(Wg + (size_t)(n0 + r) * KTOT + k0s + q * 8,                   \
                (char*)Bs[d] + s * 16);                                       \
    }                                                                         \
  }

  STAGE(0, 0);
  int cur = 0;
  for (int t = 0; t < NK; ++t) {
    // Prefetch next K-tile into the other buffer (redundant re-stage of the
    // last tile at t == NK-1 keeps the vmcnt count uniform; it lands in a
    // buffer whose reads completed before the previous end-barrier).
    int kt = t + 1 < NK ? t + 1 : NK - 1;
    STAGE(cur ^ 1, kt);
    // Counted wait: only K-tile t's 8 loads must have landed; K-tile t+1's
    // 8 stay in flight across both barriers (T4 — never drain to 0 here).
    asm volatile("s_waitcnt vmcnt(8)" ::: "memory");
    __builtin_amdgcn_s_barrier();

    const char* Ab = (const char*)As[cur];
    const char* Bb = (const char*)Bs[cur];
#pragma unroll
    for (int h = 0; h < 2; ++h) {
      bf16x8 af[8], bfr[4];
#pragma unroll
      for (int mi = 0; mi < 8; ++mi) {
        int m = wm + mi * 16 + r16;
        int slot = m * 8 + ((h * 4 + quad) ^ ((m >> 1) & 7));
        af[mi] = *(const bf16x8*)(Ab + slot * 16);
      }
#pragma unroll
      for (int ni = 0; ni < 4; ++ni) {
        int n = wn + ni * 16 + r16;
        int slot = n * 8 + ((h * 4 + quad) ^ ((n >> 1) & 7));
        bfr[ni] = *(const bf16x8*)(Bb + slot * 16);
      }
      __builtin_amdgcn_s_setprio(1);
#pragma unroll
      for (int mi = 0; mi < 8; ++mi)
#pragma unroll
        for (int ni = 0; ni < 4; ++ni)
          acc[mi][ni] = __builtin_amdgcn_mfma_f32_16x16x32_bf16(af[mi], bfr[ni], acc[mi][ni], 0, 0, 0);
      __builtin_amdgcn_s_setprio(0);
    }
    // Pin all LDS reads of this tile before the end barrier (their lgkmcnt
    // waits are compiler-inserted before the MFMAs that consume them).
    asm volatile("" ::: "memory");
    __builtin_amdgcn_s_barrier();
    cur ^= 1;
  }
  // Drain the final (redundant) stage before LDS deallocation at kernel end.
  asm volatile("s_waitcnt vmcnt(0)" ::: "memory");
#undef STAGE

  // C/D layout: col = lane&15, row = quad*4 + reg  [m89/m91]
#pragma unroll
  for (int mi = 0; mi < 8; ++mi)
#pragma unroll
    for (int ni = 0; ni < 4; ++ni)
#pragma unroll
      for (int r = 0; r < 4; ++r) {
        int row = m0 + wm + mi * 16 + quad * 4 + r;
        int cc = n0 + wn + ni * 16 + r16;
        C[(size_t)row * 1024 + cc] = acc[mi][ni][r];
      }
}

// ---------------------------------------------------------------------------
extern "C" void kernel_launch(void* const* d_in, const int* in_sizes, int n_in,
                              void* d_out, int out_size, void* d_ws, size_t ws_size,
                              hipStream_t stream) {
  const float* tokens = (const float*)d_in[0];
  const float* Wb     = (const float*)d_in[1];
  const float* A      = (const float*)d_in[2];
  const float* B      = (const float*)d_in[3];
  const float* Wg     = (const float*)d_in[4];
  float* out = (float*)d_out;

  char* ws = (char*)d_ws;
  unsigned short* Xcat  = (unsigned short*)(ws);                 // [16384][1152] bf16  37748736 B
  unsigned short* WcatT = (unsigned short*)(ws + 37748736);      // [1024][1152] bf16    2359296 B
  unsigned short* AcatT = (unsigned short*)(ws + 40108032);      // [128][1024] bf16      262144 B
  float4*         ginfo = (float4*)(ws + 40370176);              // [16384] float4       262144 B
  float*          WgT   = (float*)(ws + 40632320);               // [8][1024] fp32         32768 B

  float* out_logits = out + (size_t)16384 * 1024;
  float* out_sel    = out_logits + (size_t)16384 * 8;
  float* out_w      = out_sel + (size_t)16384 * 2;

  k_transW<<<dim3(18, 16), dim3(256), 0, stream>>>(Wb, B, WcatT);
  k_transA<<<dim3(4, 8), dim3(256), 0, stream>>>(A, AcatT);
  k_transG<<<dim3(4), dim3(256), 0, stream>>>(Wg, WgT);
  k_router<<<dim3(2048), dim3(256), 0, stream>>>(tokens, WgT, out_logits, out_sel, out_w, Xcat, ginfo);
  k_hgemm<<<dim3(512), dim3(256), 0, stream>>>(Xcat, AcatT, ginfo, Xcat);
  k_gemm_main<<<dim3(256), dim3(512), 0, stream>>>(Xcat, WcatT, out);
}

// Round 2
// 186.131 us; speedup vs baseline: 1.0093x; 1.0093x over previous
//
#include <hip/hip_runtime.h>
#include <hip/hip_bf16.h>
#include <cstdint>
#include <cfloat>

#define NTOK 16384
#define DIN  1024
#define DOUT 1024
#define NEXP 8
#define RLORA 16
#define KTOT 1152          // DIN + NEXP*RLORA
#define SCALE_LORA 2.0f    // alpha/rank = 32/16

typedef __attribute__((ext_vector_type(8))) short bf16x8;
typedef __attribute__((ext_vector_type(4))) float f32x4;

__device__ __forceinline__ unsigned short f2bf(float f) {
  __hip_bfloat16 h = __float2bfloat16(f);
  unsigned short u;
  __builtin_memcpy(&u, &h, 2);
  return u;
}

__device__ __forceinline__ void gld_lds16(const void* g, void* l) {
  __builtin_amdgcn_global_load_lds((const __attribute__((address_space(1))) void*)g,
                                   (__attribute__((address_space(3))) void*)l,
                                   16, 0, 0);
}

// ---------------------------------------------------------------------------
// k_prep: fused preprocessing (one launch instead of three).
//   bid <  288 : transW  — WcatT[j][k] = [W_base; Bcat][k][j] bf16
//   bid <  320 : transA  — AcatT[e*16+r][d] = A[e][d][r] bf16
//   bid >= 320 : transG  — WgT[e][d] = Wg[d][e] fp32
// ---------------------------------------------------------------------------
__global__ __launch_bounds__(256) void k_prep(const float* __restrict__ Wb,
                                              const float* __restrict__ B,
                                              const float* __restrict__ A,
                                              const float* __restrict__ Wg,
                                              unsigned short* __restrict__ WcatT,
                                              unsigned short* __restrict__ AcatT,
                                              float* __restrict__ WgT) {
  __shared__ unsigned short Tbuf[256 * 17];   // 8704 B, covers 64*66 too
  const int bid = blockIdx.x;
  const int t = threadIdx.x;
  if (bid < 288) {
    unsigned short (*T)[66] = (unsigned short (*)[66])Tbuf;
    const int k0 = (bid % 18) * 64, j0 = (bid / 18) * 64;
#pragma unroll
    for (int p = 0; p < 4; ++p) {
      int kk = p * 16 + (t >> 4);
      int c4 = (t & 15) * 4;
      int k = k0 + kk;
      const float* src = (k < 1024) ? (Wb + (size_t)k * 1024) : (B + (size_t)(k - 1024) * 1024);
      float4 v = *(const float4*)(src + j0 + c4);
      T[kk][c4 + 0] = f2bf(v.x); T[kk][c4 + 1] = f2bf(v.y);
      T[kk][c4 + 2] = f2bf(v.z); T[kk][c4 + 3] = f2bf(v.w);
    }
    __syncthreads();
#pragma unroll
    for (int p = 0; p < 2; ++p) {
      int jj = p * 32 + (t >> 3);
      int kc = (t & 7) * 8;
      unsigned short buf[8];
#pragma unroll
      for (int i = 0; i < 8; ++i) buf[i] = T[kc + i][jj];
      uint4 u; __builtin_memcpy(&u, buf, 16);
      *(uint4*)(WcatT + (size_t)(j0 + jj) * KTOT + k0 + kc) = u;
    }
  } else if (bid < 320) {
    unsigned short (*T)[17] = (unsigned short (*)[17])Tbuf;
    const int e = (bid - 288) >> 2, d0 = ((bid - 288) & 3) * 256;
#pragma unroll
    for (int p = 0; p < 4; ++p) {
      int idx = p * 256 + t;
      int d = idx >> 2;
      int rr = (idx & 3) * 4;
      float4 v = *(const float4*)(A + (size_t)e * 16384 + (size_t)(d0 + d) * 16 + rr);
      T[d][rr + 0] = f2bf(v.x); T[d][rr + 1] = f2bf(v.y);
      T[d][rr + 2] = f2bf(v.z); T[d][rr + 3] = f2bf(v.w);
    }
    __syncthreads();
#pragma unroll
    for (int p = 0; p < 2; ++p) {
      int slot = p * 256 + t;
      int r = slot >> 5;
      int dc = (slot & 31) * 8;
      unsigned short buf[8];
#pragma unroll
      for (int i = 0; i < 8; ++i) buf[i] = T[dc + i][r];
      uint4 u; __builtin_memcpy(&u, buf, 16);
      *(uint4*)(AcatT + (size_t)(e * 16 + r) * 1024 + d0 + dc) = u;
    }
  } else {
    int d = (bid - 320) * 256 + t;
    float4 a = *(const float4*)(Wg + (size_t)d * 8);
    float4 b = *(const float4*)(Wg + (size_t)d * 8 + 4);
    WgT[0 * 1024 + d] = a.x; WgT[1 * 1024 + d] = a.y;
    WgT[2 * 1024 + d] = a.z; WgT[3 * 1024 + d] = a.w;
    WgT[4 * 1024 + d] = b.x; WgT[5 * 1024 + d] = b.y;
    WgT[6 * 1024 + d] = b.z; WgT[7 * 1024 + d] = b.w;
  }
}

// ---------------------------------------------------------------------------
// Router: one wave per TWO tokens. grid 2048.
// ---------------------------------------------------------------------------
__global__ __launch_bounds__(256) void k_router(const float* __restrict__ tokens,
                                                const float* __restrict__ WgT,
                                                float* __restrict__ out_logits,
                                                float* __restrict__ out_sel,
                                                float* __restrict__ out_w,
                                                unsigned short* __restrict__ Xcat,
                                                float4* __restrict__ gateinfo) {
  const int wid = threadIdx.x >> 6;
  const int lane = threadIdx.x & 63;
  const int t0 = (blockIdx.x * 4 + wid) * 2;

  float4 xa[4], xb[4];
  const float* x0 = tokens + (size_t)t0 * DIN;
  const float* x1 = x0 + DIN;
#pragma unroll
  for (int j = 0; j < 4; ++j) {
    xa[j] = *(const float4*)(x0 + j * 256 + lane * 4);
    xb[j] = *(const float4*)(x1 + j * 256 + lane * 4);
  }

#pragma unroll
  for (int tt = 0; tt < 2; ++tt) {
    unsigned short* xbp = Xcat + (size_t)(t0 + tt) * KTOT;
    const float4* xv = tt ? xb : xa;
#pragma unroll
    for (int j = 0; j < 4; ++j) {
      const float* xf = (const float*)&xv[j];
      unsigned short hb[4];
#pragma unroll
      for (int m = 0; m < 4; ++m) hb[m] = f2bf(xf[m]);
      uint2 u;
      __builtin_memcpy(&u, hb, 8);
      *(uint2*)(xbp + j * 256 + lane * 4) = u;
    }
  }

  float accA[8] = {0,0,0,0,0,0,0,0}, accB[8] = {0,0,0,0,0,0,0,0};
#pragma unroll
  for (int j = 0; j < 4; ++j) {
#pragma unroll
    for (int e = 0; e < 8; ++e) {
      float4 wv = *(const float4*)(WgT + (size_t)e * 1024 + j * 256 + lane * 4);
      accA[e] = fmaf(xa[j].x, wv.x, fmaf(xa[j].y, wv.y,
                fmaf(xa[j].z, wv.z, fmaf(xa[j].w, wv.w, accA[e]))));
      accB[e] = fmaf(xb[j].x, wv.x, fmaf(xb[j].y, wv.y,
                fmaf(xb[j].z, wv.z, fmaf(xb[j].w, wv.w, accB[e]))));
    }
  }
#pragma unroll
  for (int s = 1; s < 64; s <<= 1) {
#pragma unroll
    for (int e = 0; e < 8; ++e) {
      accA[e] += __shfl_xor(accA[e], s, 64);
      accB[e] += __shfl_xor(accB[e], s, 64);
    }
  }

#pragma unroll
  for (int tt = 0; tt < 2; ++tt) {
    const float* acc = tt ? accB : accA;
    int t = t0 + tt;
    float v0 = -FLT_MAX, v1 = -FLT_MAX;
    int i0 = -1, i1 = -1;
#pragma unroll
    for (int e = 0; e < 8; ++e) {
      float v = acc[e];
      if (v > v0) { v1 = v0; i1 = i0; v0 = v; i0 = e; }
      else if (v > v1) { v1 = v; i1 = e; }
    }
    float ex = expf(v1 - v0);
    float inv = 1.0f / (1.0f + ex);
    float w0 = inv, w1 = ex * inv;
    if (lane == 0) {
      float4* lg = (float4*)(out_logits + (size_t)t * 8);
      lg[0] = make_float4(acc[0], acc[1], acc[2], acc[3]);
      lg[1] = make_float4(acc[4], acc[5], acc[6], acc[7]);
      *(float2*)(out_sel + (size_t)t * 2) = make_float2((float)i0, (float)i1);
      *(float2*)(out_w + (size_t)t * 2) = make_float2(w0, w1);
      gateinfo[t] = make_float4((float)i0, (float)i1, w0 * SCALE_LORA, w1 * SCALE_LORA);
    }
  }
}

// ---------------------------------------------------------------------------
// H-GEMM + gating. BM=64, BN=64, BK=64, grid 512.
// ---------------------------------------------------------------------------
__global__ __launch_bounds__(256) void k_hgemm(const unsigned short* __restrict__ Xg,
                                               const unsigned short* __restrict__ Ag,
                                               const float4* __restrict__ gateinfo,
                                               unsigned short* __restrict__ Xout) {
  constexpr int BK = 64;
  __shared__ alignas(16) unsigned short As[64 * BK];
  __shared__ alignas(16) unsigned short Bs[64 * BK];
  const int tid = threadIdx.x;
  const int lane = tid & 63;
  const int wid = tid >> 6;
  const int id = blockIdx.x;
  const int xcd = id & 7, s5 = id >> 3;
  const int n0 = (s5 & 1) * 64;
  const int m0 = (xcd * 32 + (s5 >> 1)) * 64;
  const int wm = (wid >> 1) * 32, wn = (wid & 1) * 32;
  const int quad = lane >> 4, r16 = lane & 15;

  f32x4 acc[2][2] = {};

  for (int k0 = 0; k0 < 1024; k0 += BK) {
#pragma unroll
    for (int i = 0; i < 2; ++i) {
      int s = i * 256 + tid;
      int r = s >> 3, c = s & 7;
      int q = c ^ ((r >> 1) & 7);
      gld_lds16(Xg + (size_t)(m0 + r) * KTOT + k0 + q * 8, (char*)As + s * 16);
    }
#pragma unroll
    for (int i = 0; i < 2; ++i) {
      int s = i * 256 + tid;
      int r = s >> 3, c = s & 7;
      int q = c ^ ((r >> 1) & 7);
      gld_lds16(Ag + (size_t)(n0 + r) * 1024 + k0 + q * 8, (char*)Bs + s * 16);
    }
    __syncthreads();

#pragma unroll
    for (int h = 0; h < 2; ++h) {
      bf16x8 af[2], bfr[2];
#pragma unroll
      for (int mi = 0; mi < 2; ++mi) {
        int m = wm + mi * 16 + r16;
        int slot = m * 8 + ((h * 4 + quad) ^ ((m >> 1) & 7));
        af[mi] = *(const bf16x8*)((const char*)As + slot * 16);
      }
#pragma unroll
      for (int ni = 0; ni < 2; ++ni) {
        int n = wn + ni * 16 + r16;
        int slot = n * 8 + ((h * 4 + quad) ^ ((n >> 1) & 7));
        bfr[ni] = *(const bf16x8*)((const char*)Bs + slot * 16);
      }
#pragma unroll
      for (int mi = 0; mi < 2; ++mi)
#pragma unroll
        for (int ni = 0; ni < 2; ++ni)
          acc[mi][ni] = __builtin_amdgcn_mfma_f32_16x16x32_bf16(af[mi], bfr[ni], acc[mi][ni], 0, 0, 0);
    }
    __syncthreads();
  }

#pragma unroll
  for (int mi = 0; mi < 2; ++mi)
#pragma unroll
    for (int r = 0; r < 4; ++r) {
      int row = m0 + wm + mi * 16 + quad * 4 + r;
      float4 gi = gateinfo[row];
      int ie0 = (int)gi.x, ie1 = (int)gi.y;
#pragma unroll
      for (int ni = 0; ni < 2; ++ni) {
        int c = n0 + wn + ni * 16 + r16;
        int e = c >> 4;
        float h = acc[mi][ni][r];
        float v = (e == ie0) ? gi.z * h : ((e == ie1) ? gi.w * h : 0.f);
        Xout[(size_t)row * KTOT + 1024 + c] = f2bf(v);
      }
    }
}

// ---------------------------------------------------------------------------
// Main GEMM, 8-phase schedule (T2+T3+T4+T5). 256x256 tile, BK=64, 8 waves
// (2Mx4N), LDS = 2 slots x {A 2x[128][64], B 2x[128][64]} = 128 KB.
// Per phase: 12 ds_read_b128 + stage issue + barrier + 16 MFMA + barrier.
// Quadrant order per K-tile: (mh,nh) = (0,0),(1,1),(1,0),(0,1).
// Stage schedule (derived from region deadness; see session notes):
//   ph0: s1.A0+s1.B0 (kt 2i+1)   ph1: s1.B1 (kt 2i+1)
//   ph3: s0.A1 (kt 2i+2) +vmcnt(2)
//   ph4: s0.A0+s0.B0 (kt 2i+2)   ph5: s0.B1 (kt 2i+2)
//   ph7: s1.A1 (kt 2i+3) +vmcnt(2)
// vmcnt(2) at ph3/ph7 guarantees the next-consumed K-tile fully landed
// (everything except the 2 loads issued in that same phase) — never 0 in
// the main loop. Last iteration restages kt=17 to keep counts uniform.
// ---------------------------------------------------------------------------
__global__ __launch_bounds__(512, 2) void k_gemm_main(const unsigned short* __restrict__ Xg,
                                                      const unsigned short* __restrict__ Wgm,
                                                      float* __restrict__ C) {
  __shared__ alignas(16) unsigned short As[2][2][128 * 64];  // 64 KB
  __shared__ alignas(16) unsigned short Bs[2][2][128 * 64];  // 64 KB
  const int tid = threadIdx.x;
  const int lane = tid & 63;
  const int wid = tid >> 6;
  const int id = blockIdx.x;
  const int xcd = id & 7, loc = id >> 3;
  const int gid = xcd * 32 + loc;           // bijective: 256 % 8 == 0
  const int m0 = (gid >> 2) * 256;          // 64 m-tiles
  const int n0 = (gid & 3) * 256;           // 4 n-tiles
  const int wr64 = (wid >> 2) * 64;         // wave m-offset within each A-half
  const int wc32 = (wid & 3) * 32;          // wave n-offset within each B-half
  const int quad = lane >> 4, r16 = lane & 15;

  f32x4 acc[2][2][4][2] = {};

  // Stage one half-tile (128 rows x 64 k, 16 KB): 2 gld_lds16 per thread.
  // Pre-swizzled global source (q = c ^ ((r>>1)&7)), linear LDS dest —
  // both-sides involution, measured 0 bank conflicts.
#define STAGE_A(SL, HF, KT)                                                   \
  {                                                                           \
    _Pragma("unroll")                                                         \
    for (int i_ = 0; i_ < 2; ++i_) {                                          \
      int s_ = i_ * 512 + tid;                                                \
      int r_ = s_ >> 3, c_ = s_ & 7;                                          \
      int q_ = c_ ^ ((r_ >> 1) & 7);                                          \
      gld_lds16(Xg + (size_t)(m0 + (HF) * 128 + r_) * KTOT + (KT) * 64 + q_ * 8, \
                (char*)As[SL][HF] + s_ * 16);                                 \
    }                                                                         \
  }
#define STAGE_B(SL, HF, KT)                                                   \
  {                                                                           \
    _Pragma("unroll")                                                         \
    for (int i_ = 0; i_ < 2; ++i_) {                                          \
      int s_ = i_ * 512 + tid;                                                \
      int r_ = s_ >> 3, c_ = s_ & 7;                                          \
      int q_ = c_ ^ ((r_ >> 1) & 7);                                          \
      gld_lds16(Wgm + (size_t)(n0 + (HF) * 128 + r_) * KTOT + (KT) * 64 + q_ * 8, \
                (char*)Bs[SL][HF] + s_ * 16);                                 \
    }                                                                         \
  }

  // One phase: ds-reads for quadrant (MH,NH) of slot SL, stage issue,
  // barrier, lgkm drain, 16 MFMA under setprio, barrier.
#define PHASE(SL, MH, NH, ...)                                                \
  {                                                                           \
    bf16x8 af[4][2], bfr[2][2];                                               \
    const char* Ab = (const char*)As[SL][MH];                                 \
    const char* Bb = (const char*)Bs[SL][NH];                                 \
    _Pragma("unroll")                                                         \
    for (int mi = 0; mi < 4; ++mi) {                                          \
      int rh = wr64 + mi * 16 + r16;                                          \
      int sw = (rh >> 1) & 7;                                                 \
      af[mi][0] = *(const bf16x8*)(Ab + (rh * 8 + (quad ^ sw)) * 16);         \
      af[mi][1] = *(const bf16x8*)(Ab + (rh * 8 + ((4 + quad) ^ sw)) * 16);   \
    }                                                                         \
    _Pragma("unroll")                                                         \
    for (int ni = 0; ni < 2; ++ni) {                                          \
      int rh = wc32 + ni * 16 + r16;                                          \
      int sw = (rh >> 1) & 7;                                                 \
      bfr[ni][0] = *(const bf16x8*)(Bb + (rh * 8 + (quad ^ sw)) * 16);        \
      bfr[ni][1] = *(const bf16x8*)(Bb + (rh * 8 + ((4 + quad) ^ sw)) * 16);  \
    }                                                                         \
    __VA_ARGS__;                                                              \
    asm volatile("" ::: "memory");                                            \
    __builtin_amdgcn_s_barrier();                                             \
    asm volatile("s_waitcnt lgkmcnt(0)" ::: "memory");                        \
    __builtin_amdgcn_sched_barrier(0);                                        \
    __builtin_amdgcn_s_setprio(1);                                            \
    _Pragma("unroll")                                                         \
    for (int mi = 0; mi < 4; ++mi)                                            \
      _Pragma("unroll")                                                       \
      for (int ni = 0; ni < 2; ++ni) {                                        \
        acc[MH][NH][mi][ni] = __builtin_amdgcn_mfma_f32_16x16x32_bf16(        \
            af[mi][0], bfr[ni][0], acc[MH][NH][mi][ni], 0, 0, 0);             \
        acc[MH][NH][mi][ni] = __builtin_amdgcn_mfma_f32_16x16x32_bf16(        \
            af[mi][1], bfr[ni][1], acc[MH][NH][mi][ni], 0, 0, 0);             \
      }                                                                       \
    __builtin_amdgcn_s_setprio(0);                                            \
    asm volatile("" ::: "memory");                                            \
    __builtin_amdgcn_s_barrier();                                             \
  }

  // Prologue: slot0 <- K-tile 0 (full), slot1.A1 <- K-tile 1 (ph7 role).
  STAGE_A(0, 0, 0); STAGE_A(0, 1, 0); STAGE_B(0, 0, 0); STAGE_B(0, 1, 0);
  STAGE_A(1, 1, 1);
  asm volatile("s_waitcnt vmcnt(2)" ::: "memory");
  __builtin_amdgcn_s_barrier();

  for (int it = 0; it < 9; ++it) {
    const int kt1 = 2 * it + 1;
    const int kt2 = (2 * it + 2 < 18) ? 2 * it + 2 : 17;
    const int kt3 = (2 * it + 3 < 18) ? 2 * it + 3 : 17;
    PHASE(0, 0, 0, STAGE_A(1, 0, kt1); STAGE_B(1, 0, kt1))
    PHASE(0, 1, 1, STAGE_B(1, 1, kt1))
    PHASE(0, 1, 0, )
    PHASE(0, 0, 1, STAGE_A(0, 1, kt2);
                   asm volatile("s_waitcnt vmcnt(2)" ::: "memory"))
    PHASE(1, 0, 0, STAGE_A(0, 0, kt2); STAGE_B(0, 0, kt2))
    PHASE(1, 1, 1, STAGE_B(0, 1, kt2))
    PHASE(1, 1, 0, )
    PHASE(1, 0, 1, STAGE_A(1, 1, kt3);
                   asm volatile("s_waitcnt vmcnt(2)" ::: "memory"))
  }
  // Drain remaining (redundant) stages before LDS goes away.
  asm volatile("s_waitcnt vmcnt(0)" ::: "memory");
#undef PHASE
#undef STAGE_A
#undef STAGE_B

  // C/D layout: col = lane&15, row = quad*4 + reg  [m89/m91]
#pragma unroll
  for (int mh = 0; mh < 2; ++mh)
#pragma unroll
    for (int nh = 0; nh < 2; ++nh)
#pragma unroll
      for (int mi = 0; mi < 4; ++mi)
#pragma unroll
        for (int ni = 0; ni < 2; ++ni)
#pragma unroll
          for (int r = 0; r < 4; ++r) {
            int row = m0 + mh * 128 + wr64 + mi * 16 + quad * 4 + r;
            int cc = n0 + nh * 128 + wc32 + ni * 16 + r16;
            C[(size_t)row * 1024 + cc] = acc[mh][nh][mi][ni][r];
          }
}

// ---------------------------------------------------------------------------
extern "C" void kernel_launch(void* const* d_in, const int* in_sizes, int n_in,
                              void* d_out, int out_size, void* d_ws, size_t ws_size,
                              hipStream_t stream) {
  const float* tokens = (const float*)d_in[0];
  const float* Wb     = (const float*)d_in[1];
  const float* A      = (const float*)d_in[2];
  const float* B      = (const float*)d_in[3];
  const float* Wg     = (const float*)d_in[4];
  float* out = (float*)d_out;

  char* ws = (char*)d_ws;
  unsigned short* Xcat  = (unsigned short*)(ws);                 // [16384][1152] bf16  37748736 B
  unsigned short* WcatT = (unsigned short*)(ws + 37748736);      // [1024][1152] bf16    2359296 B
  unsigned short* AcatT = (unsigned short*)(ws + 40108032);      // [128][1024] bf16      262144 B
  float4*         ginfo = (float4*)(ws + 40370176);              // [16384] float4       262144 B
  float*          WgT   = (float*)(ws + 40632320);               // [8][1024] fp32         32768 B

  float* out_logits = out + (size_t)16384 * 1024;
  float* out_sel    = out_logits + (size_t)16384 * 8;
  float* out_w      = out_sel + (size_t)16384 * 2;

  k_prep<<<dim3(324), dim3(256), 0, stream>>>(Wb, B, A, Wg, WcatT, AcatT, WgT);
  k_router<<<dim3(2048), dim3(256), 0, stream>>>(tokens, WgT, out_logits, out_sel, out_w, Xcat, ginfo);
  k_hgemm<<<dim3(512), dim3(256), 0, stream>>>(Xcat, AcatT, ginfo, Xcat);
  k_gemm_main<<<dim3(256), dim3(512), 0, stream>>>(Xcat, WcatT, out);
}